// Round 3
// baseline (49.842 us; speedup 1.0000x reference)
//
#include <hip/hip_runtime.h>

#define DIM 32
#define KK 64
#define WPB 4
#define WIH_STRIDE 144          // packed W_ih row: 128B data + 16 pad
#define WHH_STRIDE 80           // packed W_hh row: 64B data + 16 pad
#define H1_STRIDE 80            // h1 row: 64B data + 16 pad
#define LDS_WIH (32 * WIH_STRIDE)
#define LDS_WHH (32 * WHH_STRIDE)
#define LDS_H1  (KK * H1_STRIDE)

typedef short bf16x8 __attribute__((ext_vector_type(8)));
typedef float f32x16 __attribute__((ext_vector_type(16)));
typedef unsigned int u32x4 __attribute__((ext_vector_type(4)));

__device__ __forceinline__ float rcp_fast(float x) { return __builtin_amdgcn_rcpf(x); }

// tanh(x) = 1 - 2/(exp(2x)+1); graceful at +-inf
__device__ __forceinline__ float tanh_fast(float x) {
    float t = __expf(2.0f * x);
    return 1.0f - 2.0f * rcp_fast(t + 1.0f);
}

// pack two f32 -> one dword of 2 bf16 (truncation) via v_perm_b32
__device__ __forceinline__ unsigned pk2(float lo, float hi) {
    return __builtin_amdgcn_perm(__builtin_bit_cast(unsigned, hi),
                                 __builtin_bit_cast(unsigned, lo), 0x07060302u);
}

__device__ __forceinline__ bf16x8 pack8(float4 a, float4 b) {
    u32x4 u;
    u[0] = pk2(a.x, a.y); u[1] = pk2(a.z, a.w);
    u[2] = pk2(b.x, b.y); u[3] = pk2(b.z, b.w);
    return __builtin_bit_cast(bf16x8, u);
}

__device__ __forceinline__ float dot4(float4 a, float4 b) {
    float s = a.x * b.x;
    s = fmaf(a.y, b.y, s); s = fmaf(a.z, b.z, s); s = fmaf(a.w, b.w, s);
    return s;
}

__global__ __launch_bounds__(256) void ripple_k1(
    const int* __restrict__ users,
    const int* __restrict__ items,
    const int* __restrict__ hop0_items,
    const int* __restrict__ heads,
    const int* __restrict__ relations,
    const int* __restrict__ tails,
    const float* __restrict__ entity_emb,
    const float* __restrict__ relation_emb,
    const float* __restrict__ rec_user_emb,
    const float* __restrict__ rec_item_emb,
    const float* __restrict__ W_ih,
    const float* __restrict__ W_hh,
    const float* __restrict__ b_ih,
    const float* __restrict__ b_hh,
    float* __restrict__ ws,
    const int B)
{
    __shared__ __align__(16) unsigned char lds[LDS_WIH + LDS_WHH + WPB * LDS_H1];
    unsigned char* wihL = lds;
    unsigned char* whhL = lds + LDS_WIH;
    unsigned char* h1L  = lds + LDS_WIH + LDS_WHH;

    const int tid = threadIdx.x;

    // ---- stage packed bf16 weight images (per block, padded rows) ----
    #pragma unroll
    for (int c = 0; c < 4; ++c) {
        int i = tid + 256 * c;              // dword index 0..1023 (W_ih: 32 rows x 32 dwords)
        int row = i >> 5, dw = i & 31;
        *(unsigned*)(wihL + row * WIH_STRIDE + dw * 4) =
            pk2(W_ih[row * 64 + 2 * dw], W_ih[row * 64 + 2 * dw + 1]);
    }
    #pragma unroll
    for (int c = 0; c < 2; ++c) {
        int i = tid + 256 * c;              // 0..511 (W_hh: 32 rows x 16 dwords)
        int row = i >> 4, dw = i & 15;
        *(unsigned*)(whhL + row * WHH_STRIDE + dw * 4) =
            pk2(W_hh[row * 32 + 2 * dw], W_hh[row * 32 + 2 * dw + 1]);
    }
    __syncthreads();

    const int wv   = tid >> 6;
    const int lane = tid & 63;
    const int h5   = lane >> 5;
    const int p    = lane & 31;
    const int w    = blockIdx.x * WPB + wv;
    if (w >= 3 * B) return;

    int role, b0;
    if (w < B)          { role = 0; b0 = w; }
    else if (w < 2 * B) { role = 1; b0 = w - B; }
    else                { role = 2; b0 = w - 2 * B; }
    const int b = __builtin_amdgcn_readfirstlane(b0);

    if (role == 0) {
        // ---- hop-0 seed set + user.q ----
        const int it = __builtin_amdgcn_readfirstlane(items[b]);
        const int uu = __builtin_amdgcn_readfirstlane(users[b]);
        float q[DIM];
        #pragma unroll
        for (int d = 0; d < DIM; ++d)
            q[d] = entity_emb[(size_t)it * DIM + d] + rec_item_emb[(size_t)it * DIM + d];
        float up = 0.0f;
        #pragma unroll
        for (int d = 0; d < DIM; ++d)
            up = fmaf(rec_user_emb[(size_t)uu * DIM + d], q[d], up);

        const int idx = hop0_items[b * KK + lane];
        const float4* rp = (const float4*)(entity_emb + (size_t)idx * DIM);
        float part = 0.0f;
        #pragma unroll
        for (int i = 0; i < 8; ++i) {
            float4 v = rp[i];
            part = fmaf(v.x, q[4*i+0], part);
            part = fmaf(v.y, q[4*i+1], part);
            part = fmaf(v.z, q[4*i+2], part);
            part = fmaf(v.w, q[4*i+3], part);
        }
        #pragma unroll
        for (int m = 1; m <= 32; m <<= 1) part += __shfl_xor(part, m, 64);
        if (lane == 0) ws[b] = part + up;
        return;
    }

    // ---- hop wave: role-1 = hop index ----
    const int l = role - 1;
    const int base = (l * B + b) * KK;

    // triple indices for this lane's frag columns (p and p+32)
    const int iAh = heads[base + p],       iBh = heads[base + 32 + p];
    const int iAr = relations[base + p],   iBr = relations[base + 32 + p];
    const int iAt = tails[base + p],       iBt = tails[base + 32 + p];

    // gather directly in B-frag layout: lane (p,h5) takes octet chunks
    // [16kt+8h5, +8) of triples p (A) and p+32 (B). layout g[nt*4 + kt*2 + pair]
    float4 gh[8], gt[8], gr[8];
    {
        const float* a = entity_emb + (size_t)iAh * DIM + 8 * h5;
        const float* bb_ = entity_emb + (size_t)iBh * DIM + 8 * h5;
        gh[0] = *(const float4*)(a);      gh[1] = *(const float4*)(a + 4);
        gh[2] = *(const float4*)(a + 16); gh[3] = *(const float4*)(a + 20);
        gh[4] = *(const float4*)(bb_);      gh[5] = *(const float4*)(bb_ + 4);
        gh[6] = *(const float4*)(bb_ + 16); gh[7] = *(const float4*)(bb_ + 20);
    }
    {
        const float* a = entity_emb + (size_t)iAt * DIM + 8 * h5;
        const float* bb_ = entity_emb + (size_t)iBt * DIM + 8 * h5;
        gt[0] = *(const float4*)(a);      gt[1] = *(const float4*)(a + 4);
        gt[2] = *(const float4*)(a + 16); gt[3] = *(const float4*)(a + 20);
        gt[4] = *(const float4*)(bb_);      gt[5] = *(const float4*)(bb_ + 4);
        gt[6] = *(const float4*)(bb_ + 16); gt[7] = *(const float4*)(bb_ + 20);
    }
    {
        const float* a = relation_emb + (size_t)iAr * DIM + 8 * h5;
        const float* bb_ = relation_emb + (size_t)iBr * DIM + 8 * h5;
        gr[0] = *(const float4*)(a);      gr[1] = *(const float4*)(a + 4);
        gr[2] = *(const float4*)(a + 16); gr[3] = *(const float4*)(a + 20);
        gr[4] = *(const float4*)(bb_);      gr[5] = *(const float4*)(bb_ + 4);
        gr[6] = *(const float4*)(bb_ + 16); gr[7] = *(const float4*)(bb_ + 20);
    }

    // q and bias at this lane's C/D rows d = 8Q + 4*h5 + j  (L2/L3-hot)
    const int it = __builtin_amdgcn_readfirstlane(items[b]);
    float qf[16], bv[16];
    #pragma unroll
    for (int Q = 0; Q < 4; ++Q) {
        const int d0 = 8 * Q + 4 * h5;
        float4 qe = *(const float4*)(entity_emb   + (size_t)it * DIM + d0);
        float4 qr = *(const float4*)(rec_item_emb + (size_t)it * DIM + d0);
        float4 bi = *(const float4*)(b_ih + d0);
        float4 bh = *(const float4*)(b_hh + d0);
        qf[4*Q+0] = qe.x + qr.x; qf[4*Q+1] = qe.y + qr.y;
        qf[4*Q+2] = qe.z + qr.z; qf[4*Q+3] = qe.w + qr.w;
        bv[4*Q+0] = bi.x + bh.x; bv[4*Q+1] = bi.y + bh.y;
        bv[4*Q+2] = bi.z + bh.z; bv[4*Q+3] = bi.w + bh.w;
    }

    // ---- exact f32 scores from gather regs ----
    float scA = 0.0f, scB = 0.0f;
    #pragma unroll
    for (int i = 0; i < 4; ++i) {
        scA += dot4(gh[i], gt[i]);
        scA += dot4(gr[i], gr[i]);
    }
    #pragma unroll
    for (int i = 4; i < 8; ++i) {
        scB += dot4(gh[i], gt[i]);
        scB += dot4(gr[i], gr[i]);
    }

    // ---- pack B-frags straight from gather regs ----
    bf16x8 hf[2][2], tf[2][2], rf[2][2];
    #pragma unroll
    for (int nt = 0; nt < 2; ++nt)
        #pragma unroll
        for (int kt = 0; kt < 2; ++kt) {
            hf[nt][kt] = pack8(gh[nt*4 + kt*2], gh[nt*4 + kt*2 + 1]);
            tf[nt][kt] = pack8(gt[nt*4 + kt*2], gt[nt*4 + kt*2 + 1]);
            rf[nt][kt] = pack8(gr[nt*4 + kt*2], gr[nt*4 + kt*2 + 1]);
        }

    // ---- weight frags from block LDS ----
    bf16x8 wihF[4], whhF[2];
    #pragma unroll
    for (int kt = 0; kt < 4; ++kt)
        wihF[kt] = __builtin_bit_cast(bf16x8,
            *(const u32x4*)(wihL + p * WIH_STRIDE + kt * 32 + h5 * 16));
    #pragma unroll
    for (int kt = 0; kt < 2; ++kt)
        whhF[kt] = __builtin_bit_cast(bf16x8,
            *(const u32x4*)(whhL + p * WHH_STRIDE + kt * 32 + h5 * 16));

    // ---- MFMA chain ----
    f32x16 accA[2], accB[2];
    {
        f32x16 bias_v;
        #pragma unroll
        for (int j = 0; j < 16; ++j) bias_v[j] = bv[j];
        accA[0] = bias_v; accA[1] = bias_v;
    }
    #pragma unroll
    for (int nt = 0; nt < 2; ++nt)
        #pragma unroll
        for (int kt = 0; kt < 2; ++kt)
            accA[nt] = __builtin_amdgcn_mfma_f32_32x32x16_bf16(
                wihF[2 + kt], rf[nt][kt], accA[nt], 0, 0, 0);     // C_r
    accB[0] = accA[0]; accB[1] = accA[1];
    #pragma unroll
    for (int nt = 0; nt < 2; ++nt)
        #pragma unroll
        for (int kt = 0; kt < 2; ++kt)
            accB[nt] = __builtin_amdgcn_mfma_f32_32x32x16_bf16(
                wihF[kt], hf[nt][kt], accB[nt], 0, 0, 0);         // SH
    #pragma unroll
    for (int nt = 0; nt < 2; ++nt)
        #pragma unroll
        for (int kt = 0; kt < 2; ++kt)
            accA[nt] = __builtin_amdgcn_mfma_f32_32x32x16_bf16(
                wihF[kt], tf[nt][kt], accA[nt], 0, 0, 0);         // ST

    // ---- h1 = tanh(SH) -> LDS bounce (C/D layout -> B layout) ----
    unsigned char* myh1 = h1L + wv * LDS_H1;
    #pragma unroll
    for (int nt = 0; nt < 2; ++nt) {
        float t0[16];
        #pragma unroll
        for (int j = 0; j < 16; ++j) t0[j] = tanh_fast(accB[nt][j]);
        unsigned char* hrow = myh1 + (32 * nt + p) * H1_STRIDE;
        #pragma unroll
        for (int Q = 0; Q < 4; ++Q) {
            uint2 wq;
            wq.x = pk2(t0[4*Q+0], t0[4*Q+1]);
            wq.y = pk2(t0[4*Q+2], t0[4*Q+3]);
            *(uint2*)(hrow + 16 * Q + 8 * h5) = wq;
        }
    }
    #pragma unroll
    for (int nt = 0; nt < 2; ++nt)
        #pragma unroll
        for (int kt = 0; kt < 2; ++kt) {
            bf16x8 h1f = __builtin_bit_cast(bf16x8,
                *(const u32x4*)(myh1 + (32 * nt + p) * H1_STRIDE + (2 * kt + h5) * 16));
            accA[nt] = __builtin_amdgcn_mfma_f32_32x32x16_bf16(
                whhF[kt], h1f, accA[nt], 0, 0, 0);                // PRE = ST + W_hh.h1
        }

    // ---- h2 = tanh(PRE); dots; softmax-weighted sum ----
    scA += __shfl_xor(scA, 32, 64);
    scB += __shfl_xor(scB, 32, 64);
    const float e0 = __expf(scA);
    const float e1 = __expf(scB);

    float sd0 = 0.0f, sd1 = 0.0f;
    #pragma unroll
    for (int j = 0; j < 16; ++j) sd0 = fmaf(tanh_fast(accA[0][j]), qf[j], sd0);
    #pragma unroll
    for (int j = 0; j < 16; ++j) sd1 = fmaf(tanh_fast(accA[1][j]), qf[j], sd1);
    sd0 += __shfl_xor(sd0, 32, 64);
    sd1 += __shfl_xor(sd1, 32, 64);

    float num = e0 * sd0 + e1 * sd1;
    float den = e0 + e1;
    #pragma unroll
    for (int m = 1; m <= 16; m <<= 1) {
        num += __shfl_xor(num, m, 64);
        den += __shfl_xor(den, m, 64);
    }
    if (lane == 0) ws[(1 + l) * B + b] = num * rcp_fast(den);
}

__global__ __launch_bounds__(256) void ripple_k2(
    const float* __restrict__ ws, float* __restrict__ out, const int B)
{
    const int i = blockIdx.x * 256 + threadIdx.x;
    if (i < B) {
        const float s = ws[i] + ws[B + i] + ws[2 * B + i];
        out[i] = rcp_fast(1.0f + __expf(-s));
    }
}

extern "C" void kernel_launch(void* const* d_in, const int* in_sizes, int n_in,
                              void* d_out, int out_size, void* d_ws, size_t ws_size,
                              hipStream_t stream)
{
    const int* users = (const int*)d_in[0];
    const int* items = (const int*)d_in[1];
    const int* hop0  = (const int*)d_in[2];
    const int* heads = (const int*)d_in[3];
    const int* rels  = (const int*)d_in[4];
    const int* tails = (const int*)d_in[5];
    const float* entity_emb   = (const float*)d_in[6];
    const float* relation_emb = (const float*)d_in[7];
    const float* rec_user_emb = (const float*)d_in[8];
    const float* rec_item_emb = (const float*)d_in[9];
    const float* W_ih = (const float*)d_in[10];
    const float* W_hh = (const float*)d_in[11];
    const float* b_ih = (const float*)d_in[12];
    const float* b_hh = (const float*)d_in[13];
    float* out = (float*)d_out;
    float* ws  = (float*)d_ws;

    const int B = in_sizes[0];
    const int blocks1 = (3 * B + WPB - 1) / WPB;
    hipLaunchKernelGGL(ripple_k1, dim3(blocks1), dim3(256), 0, stream,
                       users, items, hop0, heads, rels, tails,
                       entity_emb, relation_emb, rec_user_emb, rec_item_emb,
                       W_ih, W_hh, b_ih, b_hh, ws, B);
    const int blocks2 = (B + 255) / 256;
    hipLaunchKernelGGL(ripple_k2, dim3(blocks2), dim3(256), 0, stream,
                       ws, out, B);
}